// Round 6
// baseline (287.559 us; speedup 1.0000x reference)
//
#include <hip/hip_runtime.h>
#include <hip/hip_bf16.h>
#include <cstdint>

// Shapes fixed by the reference: B=4, T=2048, D=512, H=8, hd=64, MAX_RADIUS=16.
#define T_LEN 2048
#define B_SZ 4
#define D_MOD 512
#define N_HEAD 8
#define HDIM 64
#define QKV_N 1536
#define M_ROWS 8192   // B*T
#define GRID_BLKS 512

typedef uint32_t u32;
typedef uint16_t u16;
typedef __attribute__((ext_vector_type(8))) __bf16 bf16x8;
typedef __attribute__((ext_vector_type(4))) float f32x4;

__device__ __forceinline__ u16 f2bf(float f) {
    u32 u = __builtin_bit_cast(u32, f);
    u32 r = (u + 0x7FFFu + ((u >> 16) & 1u)) >> 16;   // RNE
    return (u16)r;
}
__device__ __forceinline__ float bf2f(u16 h) {
    u32 u = ((u32)h) << 16;
    return __builtin_bit_cast(float, u);
}

// ---------------- device-scope grid barrier (no cooperative API) ----------------
// R5 lesson: RMW-polling (atomicAdd(cnt,0)) from 511 blocks saturates the
// same-address atomic unit (~1 RMW/cyc arrival vs ~1/20cyc service) -> tens of
// µs per barrier. Poll with plain agent-scope relaxed LOADS (no serialization)
// + s_sleep backoff; only the arrival is an RMW.
__global__ void init_bar(u32* bar) {
    if (threadIdx.x < 16) bar[threadIdx.x] = 0u;
}

__device__ __forceinline__ void grid_barrier(u32* cnt, u32 target) {
    __syncthreads();
    if (threadIdx.x == 0) {
        __threadfence();                       // release: drain dirty lines to coherence point
        __hip_atomic_fetch_add(cnt, 1u, __ATOMIC_RELAXED, __HIP_MEMORY_SCOPE_AGENT);
        while (__hip_atomic_load(cnt, __ATOMIC_RELAXED, __HIP_MEMORY_SCOPE_AGENT) < target)
            __builtin_amdgcn_s_sleep(32);      // ~2048 cyc between polls
        __threadfence();                       // acquire: invalidate stale caches
    }
    __syncthreads();
}

// ================= GEMM tile: C[M,N] = A[M,K]*B[N,K]^T + bias, bf16, BK=64 =================
// R3-proven structure: 4 waves 2x2, BN=128, global_load_lds width=16, XOR chunk swizzle.
#define BK 64

template <bool OUT_BF16, int BMt>
__device__ __forceinline__
void gemm_tile(const u16* __restrict__ A, const u16* __restrict__ B,
               const float* __restrict__ bias, void* __restrict__ C,
               int M, int N, int K, int bm, int bn,
               u16* lda, u16* ldb, int tid)
{
    constexpr int WM = BMt / 2;     // wave tile rows
    constexpr int MI = WM / 16;     // acc tiles along M per wave
    const int wave = tid >> 6;
    const int lane = tid & 63;
    const int wm = wave >> 1, wn = wave & 1;

    f32x4 acc[MI][4] = {};

    const int srow8 = lane >> 3;               // 0..7 row within 8-row group
    const int sg    = (lane & 7) ^ srow8;      // swizzled global 8-elem chunk
    const long a_base = (long)bm * BMt;
    const long b_base = (long)bn * 128;

    const int fr = lane & 15;
    const int fq = lane >> 4;
    int a_off[MI], b_off[4];
#pragma unroll
    for (int i = 0; i < MI; ++i) {
        int ra = wm * WM + i * 16 + fr;
        a_off[i] = ra * BK + ((fq ^ (ra & 7)) * 8);
    }
#pragma unroll
    for (int i = 0; i < 4; ++i) {
        int rb = wn * 64 + i * 16 + fr;
        b_off[i] = rb * BK + ((fq ^ (rb & 7)) * 8);
    }

    for (int kk = 0; kk < K; kk += BK) {
#pragma unroll
        for (int j = 0; j < BMt / 32; ++j) {
            int r = wave * (BMt / 4) + j * 8 + srow8;
            const u16* ga = A + (a_base + r) * (long)K + kk + sg * 8;
            __builtin_amdgcn_global_load_lds(
                (const __attribute__((address_space(1))) void*)ga,
                (__attribute__((address_space(3))) void*)&lda[(wave * (BMt / 4) + j * 8) * BK],
                16, 0, 0);
        }
#pragma unroll
        for (int j = 0; j < 4; ++j) {
            int r = wave * 32 + j * 8 + srow8;
            const u16* gb = B + (b_base + r) * (long)K + kk + sg * 8;
            __builtin_amdgcn_global_load_lds(
                (const __attribute__((address_space(1))) void*)gb,
                (__attribute__((address_space(3))) void*)&ldb[(wave * 32 + j * 8) * BK],
                16, 0, 0);
        }
        __syncthreads();
#pragma unroll
        for (int kh = 0; kh < 2; ++kh) {
            bf16x8 af[MI], bfr[4];
#pragma unroll
            for (int i = 0; i < MI; ++i) af[i]  = *(const bf16x8*)&lda[a_off[i] ^ (kh << 5)];
#pragma unroll
            for (int i = 0; i < 4; ++i) bfr[i] = *(const bf16x8*)&ldb[b_off[i] ^ (kh << 5)];
#pragma unroll
            for (int mi = 0; mi < MI; ++mi)
#pragma unroll
                for (int ni = 0; ni < 4; ++ni)
                    acc[mi][ni] = __builtin_amdgcn_mfma_f32_16x16x32_bf16(
                        af[mi], bfr[ni], acc[mi][ni], 0, 0, 0);
        }
        __syncthreads();
    }

    // epilogue: C/D layout col=lane&15, row=(lane>>4)*4+reg
    const long row0 = a_base + wm * WM;
    const long col0 = b_base + wn * 64;
#pragma unroll
    for (int mi = 0; mi < MI; ++mi) {
#pragma unroll
        for (int ni = 0; ni < 4; ++ni) {
            long col = col0 + ni * 16 + fr;
            float bv = bias[col];
            long rowb = row0 + mi * 16 + fq * 4;
#pragma unroll
            for (int rr = 0; rr < 4; ++rr) {
                float v = acc[mi][ni][rr] + bv;
                long idx = (rowb + rr) * (long)N + col;
                if (OUT_BF16) ((u16*)C)[idx] = f2bf(v);
                else          ((float*)C)[idx] = v;
            }
        }
    }
}

// ================= banded attention, AQ=64 single-query (LDS 26.9 KB) =================
#define AQ 64
#define AW 16
#define AROWS 96              // AQ + 2*AW
#define ASTR 70               // row stride elems; chunk g at g*18 -> conflict-light

__device__ __forceinline__ void unpack16(const u32* __restrict__ src, float* __restrict__ dst) {
#pragma unroll
    for (int dd = 0; dd < 8; ++dd) {
        u32 wv = src[dd];
        dst[2 * dd]     = bf2f((u16)(wv & 0xffffu));
        dst[2 * dd + 1] = bf2f((u16)(wv >> 16));
    }
}

__device__ __forceinline__
void attn_block64(const u16* __restrict__ qkv, const float* __restrict__ radius,
                  u16* __restrict__ out, int id, int tid, u16* ks, u16* vs)
{
    const int qc = id & 31;           // 32 chunks of 64 queries per (b,h)
    const int h  = (id >> 5) & 7;
    const int b  = id >> 8;
    const int q0 = qc * AQ;

    float rad = radius[h];
    float r = fmaxf(16.0f / (1.0f + __expf(-rad)), 1.0f);
    const int w = (int)floorf(r);       // 1..15

    // stage K/V window [q0-16, q0+79], clamped rows (masked later)
    for (int cid = tid; cid < AROWS * 4; cid += 256) {
        int row = cid >> 2;
        int ch  = cid & 3;
        int t = min(max(q0 - AW + row, 0), T_LEN - 1);
        const u16* gk = qkv + ((long)(b * T_LEN + t)) * QKV_N + D_MOD + h * HDIM + ch * 16;
        const u16* gv = gk + D_MOD;
        uint4 k0 = *(const uint4*)gk, k1 = *(const uint4*)(gk + 8);
        uint4 v0 = *(const uint4*)gv, v1 = *(const uint4*)(gv + 8);
        u32* kd = (u32*)&ks[row * ASTR + ch * 18];
        u32* vd = (u32*)&vs[row * ASTR + ch * 18];
        kd[0] = k0.x; kd[1] = k0.y; kd[2] = k0.z; kd[3] = k0.w;
        kd[4] = k1.x; kd[5] = k1.y; kd[6] = k1.z; kd[7] = k1.w;
        vd[0] = v0.x; vd[1] = v0.y; vd[2] = v0.z; vd[3] = v0.w;
        vd[4] = v1.x; vd[5] = v1.y; vd[6] = v1.z; vd[7] = v1.w;
    }

    const int qi = tid >> 2;         // query 0..63
    const int g  = tid & 3;          // dim group (16 dims)
    const int q  = q0 + qi;
    const long rowq = (long)(b * T_LEN + q);

    float qreg[16];
    {
        const u16* gq = qkv + rowq * QKV_N + h * HDIM + g * 16;
        uint4 t0 = *(const uint4*)gq, t1 = *(const uint4*)(gq + 8);
        u32 ww[8] = {t0.x, t0.y, t0.z, t0.w, t1.x, t1.y, t1.z, t1.w};
#pragma unroll
        for (int j = 0; j < 8; ++j) {
            qreg[2 * j]     = bf2f((u16)(ww[j] & 0xffffu)) * 0.125f;
            qreg[2 * j + 1] = bf2f((u16)(ww[j] >> 16))     * 0.125f;
        }
    }
    __syncthreads();

    float m = -1e30f, l = 0.0f;
    float acc[16];
#pragma unroll
    for (int d = 0; d < 16; ++d) acc[d] = 0.0f;

    for (int rel = -w; rel <= w; ++rel) {
        int j = q + rel;
        if (((unsigned)j) >= (unsigned)T_LEN) continue;   // uniform across 4-lane group
        int row = qi + AW + rel;
        float kf[16];
        unpack16((const u32*)&ks[row * ASTR + g * 18], kf);
        float s = 0.0f;
#pragma unroll
        for (int d = 0; d < 16; ++d) s += qreg[d] * kf[d];
        s += __shfl_xor(s, 1);
        s += __shfl_xor(s, 2);
        float mn = fmaxf(m, s);
        float sc = __expf(m - mn);
        float p  = __expf(s - mn);
        m = mn;
        l = l * sc + p;
        float vf[16];
        unpack16((const u32*)&vs[row * ASTR + g * 18], vf);
#pragma unroll
        for (int d = 0; d < 16; ++d) acc[d] = acc[d] * sc + p * vf[d];
    }

    float inv = 1.0f / l;   // rel=0 always in band
    u32 o[8];
#pragma unroll
    for (int j2 = 0; j2 < 8; ++j2)
        o[j2] = (u32)f2bf(acc[2 * j2] * inv) | ((u32)f2bf(acc[2 * j2 + 1] * inv) << 16);
    u16* po = out + rowq * D_MOD + h * HDIM + g * 16;
    *(uint4*)po       = make_uint4(o[0], o[1], o[2], o[3]);
    *(uint4*)(po + 8) = make_uint4(o[4], o[5], o[6], o[7]);
}

// ================= fused persistent kernel, custom grid barriers =================
// Grid 512 x 256, __launch_bounds__(256,2): VGPR<=128/wave, LDS 32KB -> 2 blocks/CU
// by capacity -> all 512 blocks co-resident -> spin barrier cannot deadlock.
// All phases give every block an IDENTICAL tile count (P1: 3, P2: 2, P3: 1) so no
// block idles at a barrier while peers work.
__global__ __launch_bounds__(256, 2)
void fused_kernel(const float* __restrict__ x, const float* __restrict__ radius,
                  const float* __restrict__ w_in, const float* __restrict__ b_in,
                  const float* __restrict__ w_out, const float* __restrict__ b_out,
                  float* __restrict__ out,
                  u16* __restrict__ x_bf, u16* __restrict__ win_bf,
                  u16* __restrict__ wout_bf, u16* __restrict__ qkv_bf,
                  u16* __restrict__ attn_bf, u32* __restrict__ bar)
{
    __shared__ alignas(16) u16 smem[16384];   // 32 KB: gemm 4096+8192 or 8192+8192, attn 13440
    const int tid = threadIdx.x;
    const int bid = blockIdx.x;

    // ---- P0: cast f32 -> bf16 (x, w_in, w_out). 655360 chunks / 131072 thr = 5 exact.
    {
        const int na = M_ROWS * D_MOD;      // 4194304
        const int nb = QKV_N * D_MOD;       // 786432
        int c = bid * 256 + tid;
#pragma unroll
        for (int it = 0; it < 5; ++it, c += GRID_BLKS * 256) {
            int i8 = c * 8;
            const float* src; u16* dst; int off;
            if (i8 < na)           { src = x;     dst = x_bf;    off = i8; }
            else if (i8 < na + nb) { src = w_in;  dst = win_bf;  off = i8 - na; }
            else                   { src = w_out; dst = wout_bf; off = i8 - na - nb; }
            const float4* pp = (const float4*)(src + off);
            float4 a = pp[0], bq = pp[1];
            u32 r0 = (u32)f2bf(a.x) | ((u32)f2bf(a.y) << 16);
            u32 r1 = (u32)f2bf(a.z) | ((u32)f2bf(a.w) << 16);
            u32 r2 = (u32)f2bf(bq.x) | ((u32)f2bf(bq.y) << 16);
            u32 r3 = (u32)f2bf(bq.z) | ((u32)f2bf(bq.w) << 16);
            *(uint4*)(dst + off) = make_uint4(r0, r1, r2, r3);
        }
    }
    grid_barrier(bar + 0, GRID_BLKS);

    // ---- P1: QKV GEMM [8192,1536]. BM=64 -> 1536 tiles = exactly 3 per block.
#pragma unroll
    for (int i = 0; i < 3; ++i) {
        int t = bid + i * GRID_BLKS;
        gemm_tile<true, 64>(x_bf, win_bf, b_in, qkv_bf,
                            M_ROWS, QKV_N, D_MOD, t & 127, t >> 7,
                            smem, smem + 64 * BK, tid);
    }
    grid_barrier(bar + 1, GRID_BLKS);

    // ---- P2: banded attention. 1024 AQ=64 chunks, exactly 2 per block.
    attn_block64(qkv_bf, radius, attn_bf, bid, tid, smem, smem + AROWS * ASTR);
    __syncthreads();
    attn_block64(qkv_bf, radius, attn_bf, bid + GRID_BLKS, tid, smem, smem + AROWS * ASTR);
    grid_barrier(bar + 2, GRID_BLKS);

    // ---- P3: out-proj GEMM [8192,512]. 512 BM=64 tiles, exactly 1 per block.
    gemm_tile<false, 64>(attn_bf, wout_bf, b_out, out,
                         M_ROWS, D_MOD, D_MOD, bid >> 2, bid & 3,
                         smem, smem + 64 * BK, tid);
}

// ================= launch =================
extern "C" void kernel_launch(void* const* d_in, const int* in_sizes, int n_in,
                              void* d_out, int out_size, void* d_ws, size_t ws_size,
                              hipStream_t stream)
{
    (void)in_sizes; (void)n_in; (void)out_size; (void)ws_size;
    const float* x      = (const float*)d_in[0];
    const float* radius = (const float*)d_in[1];
    const float* w_in   = (const float*)d_in[2];
    const float* b_in   = (const float*)d_in[3];
    const float* w_out  = (const float*)d_in[4];
    const float* b_out  = (const float*)d_in[5];
    float* outp = (float*)d_out;

    char* ws = (char*)d_ws;
    u16* x_bf    = (u16*)ws;  ws += (size_t)M_ROWS * D_MOD * 2;
    u16* win_bf  = (u16*)ws;  ws += (size_t)QKV_N * D_MOD * 2;
    u16* wout_bf = (u16*)ws;  ws += (size_t)D_MOD * D_MOD * 2;
    u16* qkv_bf  = (u16*)ws;  ws += (size_t)M_ROWS * QKV_N * 2;
    u16* attn_bf = (u16*)ws;  ws += (size_t)M_ROWS * D_MOD * 2;
    u32* bar     = (u32*)ws;   // 16 counters, zeroed by init_bar each call

    init_bar<<<1, 64, 0, stream>>>(bar);
    fused_kernel<<<GRID_BLKS, 256, 0, stream>>>(
        x, radius, w_in, b_in, w_out, b_out, outp,
        x_bf, win_bf, wout_bf, qkv_bf, attn_bf, bar);
}

// Round 7
// 126.747 us; speedup vs baseline: 2.2688x; 2.2688x over previous
//
#include <hip/hip_runtime.h>
#include <hip/hip_bf16.h>
#include <cstdint>

// Shapes fixed by the reference: B=4, T=2048, D=512, H=8, hd=64, MAX_RADIUS=16.
// R5/R6 lesson: in-kernel device-scope fences (buffer_wbl2/buffer_inv per block)
// cost ~200 us; kernel-launch boundaries are the efficient coherence mechanism.
// -> multi-kernel structure is the right one on CDNA4.
#define T_LEN 2048
#define B_SZ 4
#define D_MOD 512
#define N_HEAD 8
#define HDIM 64
#define QKV_N 1536
#define M_ROWS 8192   // B*T

typedef uint32_t u32;
typedef uint16_t u16;
typedef __attribute__((ext_vector_type(8))) __bf16 bf16x8;
typedef __attribute__((ext_vector_type(4))) float f32x4;

__device__ __forceinline__ u16 f2bf(float f) {
    u32 u = __builtin_bit_cast(u32, f);
    u32 r = (u + 0x7FFFu + ((u >> 16) & 1u)) >> 16;   // RNE
    return (u16)r;
}
__device__ __forceinline__ float bf2f(u16 h) {
    u32 u = ((u32)h) << 16;
    return __builtin_bit_cast(float, u);
}

// ---------------- fused cast f32 -> bf16 for all three inputs ----------------
__global__ void cast3_kernel(const float* __restrict__ a, int na,
                             const float* __restrict__ b, int nb,
                             const float* __restrict__ c,
                             u16* __restrict__ oa, u16* __restrict__ ob, u16* __restrict__ oc) {
    int i8 = (blockIdx.x * blockDim.x + threadIdx.x) * 8;
    const float* src; u16* dst; int off;
    if (i8 < na)           { src = a; dst = oa; off = i8; }
    else if (i8 < na + nb) { src = b; dst = ob; off = i8 - na; }
    else                   { src = c; dst = oc; off = i8 - na - nb; }
    const float4* p = (const float4*)(src + off);
    float4 x = p[0], y = p[1];
    u32 r0 = (u32)f2bf(x.x) | ((u32)f2bf(x.y) << 16);
    u32 r1 = (u32)f2bf(x.z) | ((u32)f2bf(x.w) << 16);
    u32 r2 = (u32)f2bf(y.x) | ((u32)f2bf(y.y) << 16);
    u32 r3 = (u32)f2bf(y.z) | ((u32)f2bf(y.w) << 16);
    *(uint4*)(dst + off) = make_uint4(r0, r1, r2, r3);
}

// ---------------- GEMM: C[M,N] = A[M,K] * B[N,K]^T + bias, bf16 in ----------------
// BK=64, 4 waves in 2x2. Wave tile = (BMt/2) x (BNt/2); MI=BMt/32 x NI=BNt/32 MFMA grid.
// GEMM1 uses BMt=128,BNt=192 (intensity 3.1 MFLOP / 40KB staged vs 2.1/32KB at 128x128,
// and N=1536/192 -> exactly 512 tiles). GEMM2 keeps proven 64x128.
// Staging: lane l stages global 16B chunk (l&7)^(l>>3) of its 8-row group at linear
// LDS chunk l (global_load_lds is uniform-base + lane*16); fragment for global chunk
// G=kh*4+fq of row r sits at LDS chunk G^(r&7) -> 2-way bank spread = free.
#define BK 64

template <bool OUT_BF16, int BMt, int BNt>
__global__ __launch_bounds__(256, 2)
void gemm_bt(const u16* __restrict__ A, const u16* __restrict__ B,
             const float* __restrict__ bias, void* __restrict__ C,
             int M, int N, int K)
{
    constexpr int WM = BMt / 2;     // wave tile rows
    constexpr int WN = BNt / 2;     // wave tile cols
    constexpr int MI = WM / 16;
    constexpr int NI = WN / 16;
    __shared__ alignas(16) u16 lda[BMt * BK];
    __shared__ alignas(16) u16 ldb[BNt * BK];
    const int tid  = threadIdx.x;
    const int wave = tid >> 6;
    const int lane = tid & 63;
    const int bn = blockIdx.x, bm = blockIdx.y;
    const int wm = wave >> 1, wn = wave & 1;

    f32x4 acc[MI][NI] = {};

    const int srow8 = lane >> 3;               // 0..7 row within 8-row group
    const int sg    = (lane & 7) ^ srow8;      // swizzled global 8-elem chunk
    const long a_base = (long)bm * BMt;
    const long b_base = (long)bn * BNt;

    const int fr = lane & 15;
    const int fq = lane >> 4;
    int a_off[MI], b_off[NI];
#pragma unroll
    for (int i = 0; i < MI; ++i) {
        int ra = wm * WM + i * 16 + fr;
        a_off[i] = ra * BK + ((fq ^ (ra & 7)) * 8);
    }
#pragma unroll
    for (int i = 0; i < NI; ++i) {
        int rb = wn * WN + i * 16 + fr;
        b_off[i] = rb * BK + ((fq ^ (rb & 7)) * 8);
    }

    for (int kk = 0; kk < K; kk += BK) {
#pragma unroll
        for (int j = 0; j < BMt / 32; ++j) {
            int r = wave * (BMt / 4) + j * 8 + srow8;
            const u16* ga = A + (a_base + r) * (long)K + kk + sg * 8;
            __builtin_amdgcn_global_load_lds(
                (const __attribute__((address_space(1))) void*)ga,
                (__attribute__((address_space(3))) void*)&lda[(wave * (BMt / 4) + j * 8) * BK],
                16, 0, 0);
        }
#pragma unroll
        for (int j = 0; j < BNt / 32; ++j) {
            int r = wave * (BNt / 4) + j * 8 + srow8;
            const u16* gb = B + (b_base + r) * (long)K + kk + sg * 8;
            __builtin_amdgcn_global_load_lds(
                (const __attribute__((address_space(1))) void*)gb,
                (__attribute__((address_space(3))) void*)&ldb[(wave * (BNt / 4) + j * 8) * BK],
                16, 0, 0);
        }
        __syncthreads();
#pragma unroll
        for (int kh = 0; kh < 2; ++kh) {
            bf16x8 af[MI], bfr[NI];
#pragma unroll
            for (int i = 0; i < MI; ++i) af[i]  = *(const bf16x8*)&lda[a_off[i] ^ (kh << 5)];
#pragma unroll
            for (int i = 0; i < NI; ++i) bfr[i] = *(const bf16x8*)&ldb[b_off[i] ^ (kh << 5)];
#pragma unroll
            for (int mi = 0; mi < MI; ++mi)
#pragma unroll
                for (int ni = 0; ni < NI; ++ni)
                    acc[mi][ni] = __builtin_amdgcn_mfma_f32_16x16x32_bf16(
                        af[mi], bfr[ni], acc[mi][ni], 0, 0, 0);
        }
        __syncthreads();
    }

    // epilogue: C/D layout col=lane&15, row=(lane>>4)*4+reg
    const long row0 = a_base + wm * WM;
    const long col0 = b_base + wn * WN;
#pragma unroll
    for (int mi = 0; mi < MI; ++mi) {
#pragma unroll
        for (int ni = 0; ni < NI; ++ni) {
            long col = col0 + ni * 16 + fr;
            float bv = bias[col];
            long rowb = row0 + mi * 16 + fq * 4;
#pragma unroll
            for (int rr = 0; rr < 4; ++rr) {
                float v = acc[mi][ni][rr] + bv;
                long idx = (rowb + rr) * (long)N + col;
                if (OUT_BF16) ((u16*)C)[idx] = f2bf(v);
                else          ((float*)C)[idx] = v;
            }
        }
    }
}

// ---------------- banded attention, query-pair version (R2/R3-proven) ----------------
#define AQ 128
#define AW 16
#define AROWS (AQ + 2 * AW)   // 160
#define ASTR 70

__device__ __forceinline__ void unpack16(const u32* __restrict__ src, float* __restrict__ dst) {
#pragma unroll
    for (int dd = 0; dd < 8; ++dd) {
        u32 wv = src[dd];
        dst[2 * dd]     = bf2f((u16)(wv & 0xffffu));
        dst[2 * dd + 1] = bf2f((u16)(wv >> 16));
    }
}

__global__ __launch_bounds__(256)
void attn_kernel(const u16* __restrict__ qkv, const float* __restrict__ radius,
                 u16* __restrict__ out)
{
    __shared__ u16 ks[AROWS * ASTR];
    __shared__ u16 vs[AROWS * ASTR];

    const int tid = threadIdx.x;
    const int bid = blockIdx.x;
    const int qc = bid & 15;
    const int h  = (bid >> 4) & 7;
    const int b  = bid >> 7;
    const int q0 = qc * AQ;

    float rad = radius[h];
    float r = fmaxf(16.0f / (1.0f + __expf(-rad)), 1.0f);
    const int w = (int)floorf(r);       // 1..15

    for (int cid = tid; cid < AROWS * 4; cid += 256) {
        int row = cid >> 2;
        int ch  = cid & 3;
        int t = min(max(q0 - AW + row, 0), T_LEN - 1);
        const u16* gk = qkv + ((long)(b * T_LEN + t)) * QKV_N + D_MOD + h * HDIM + ch * 16;
        const u16* gv = gk + D_MOD;
        uint4 k0 = *(const uint4*)gk, k1 = *(const uint4*)(gk + 8);
        uint4 v0 = *(const uint4*)gv, v1 = *(const uint4*)(gv + 8);
        u32* kd = (u32*)&ks[row * ASTR + ch * 18];
        u32* vd = (u32*)&vs[row * ASTR + ch * 18];
        kd[0] = k0.x; kd[1] = k0.y; kd[2] = k0.z; kd[3] = k0.w;
        kd[4] = k1.x; kd[5] = k1.y; kd[6] = k1.z; kd[7] = k1.w;
        vd[0] = v0.x; vd[1] = v0.y; vd[2] = v0.z; vd[3] = v0.w;
        vd[4] = v1.x; vd[5] = v1.y; vd[6] = v1.z; vd[7] = v1.w;
    }

    const int p = tid >> 2;          // pair index 0..63
    const int g = tid & 3;           // dim group (16 dims)
    const int qA = q0 + 2 * p;
    const long rowA = (long)(b * T_LEN + qA);
    const long rowB = rowA + 1;

    float qregA[16], qregB[16];
    {
        const u16* gq = qkv + rowA * QKV_N + h * HDIM + g * 16;
        u32 wa[8], wb[8];
        uint4 t0 = *(const uint4*)gq,              t1 = *(const uint4*)(gq + 8);
        uint4 t2 = *(const uint4*)(gq + QKV_N),    t3 = *(const uint4*)(gq + QKV_N + 8);
        wa[0]=t0.x; wa[1]=t0.y; wa[2]=t0.z; wa[3]=t0.w; wa[4]=t1.x; wa[5]=t1.y; wa[6]=t1.z; wa[7]=t1.w;
        wb[0]=t2.x; wb[1]=t2.y; wb[2]=t2.z; wb[3]=t2.w; wb[4]=t3.x; wb[5]=t3.y; wb[6]=t3.z; wb[7]=t3.w;
#pragma unroll
        for (int j = 0; j < 8; ++j) {
            qregA[2 * j]     = bf2f((u16)(wa[j] & 0xffffu)) * 0.125f;
            qregA[2 * j + 1] = bf2f((u16)(wa[j] >> 16))     * 0.125f;
            qregB[2 * j]     = bf2f((u16)(wb[j] & 0xffffu)) * 0.125f;
            qregB[2 * j + 1] = bf2f((u16)(wb[j] >> 16))     * 0.125f;
        }
    }
    __syncthreads();

    float mA = -1e30f, lA = 0.0f, mB = -1e30f, lB = 0.0f;
    float accA[16], accB[16];
#pragma unroll
    for (int d = 0; d < 16; ++d) { accA[d] = 0.0f; accB[d] = 0.0f; }

    const int imax = 2 * w + 1;
    for (int i = 0; i <= imax; ++i) {
        int jrow = 2 * p - w + i;
        int j = q0 + jrow;
        int row = jrow + AW;
        float kf[16];
        unpack16((const u32*)&ks[row * ASTR + g * 18], kf);
        float sA = 0.0f, sB = 0.0f;
#pragma unroll
        for (int d = 0; d < 16; ++d) { sA += qregA[d] * kf[d]; sB += qregB[d] * kf[d]; }
        sA += __shfl_xor(sA, 1); sA += __shfl_xor(sA, 2);
        sB += __shfl_xor(sB, 1); sB += __shfl_xor(sB, 2);
        bool inb = ((unsigned)j) < (unsigned)T_LEN;
        bool vA = inb && (i < imax);
        bool vB = inb && (i > 0);
        float mnA = fmaxf(mA, vA ? sA : -1e30f);
        float scA = __expf(mA - mnA);
        float pA  = vA ? __expf(sA - mnA) : 0.0f;
        mA = mnA; lA = lA * scA + pA;
        float mnB = fmaxf(mB, vB ? sB : -1e30f);
        float scB = __expf(mB - mnB);
        float pB  = vB ? __expf(sB - mnB) : 0.0f;
        mB = mnB; lB = lB * scB + pB;
        float vf[16];
        unpack16((const u32*)&vs[row * ASTR + g * 18], vf);
#pragma unroll
        for (int d = 0; d < 16; ++d) {
            accA[d] = accA[d] * scA + pA * vf[d];
            accB[d] = accB[d] * scB + pB * vf[d];
        }
    }

    float invA = 1.0f / lA;
    float invB = 1.0f / lB;
    u32 oA[8], oB[8];
#pragma unroll
    for (int j2 = 0; j2 < 8; ++j2) {
        oA[j2] = (u32)f2bf(accA[2 * j2] * invA) | ((u32)f2bf(accA[2 * j2 + 1] * invA) << 16);
        oB[j2] = (u32)f2bf(accB[2 * j2] * invB) | ((u32)f2bf(accB[2 * j2 + 1] * invB) << 16);
    }
    u16* poA = out + rowA * D_MOD + h * HDIM + g * 16;
    u16* poB = out + rowB * D_MOD + h * HDIM + g * 16;
    *(uint4*)poA       = make_uint4(oA[0], oA[1], oA[2], oA[3]);
    *(uint4*)(poA + 8) = make_uint4(oA[4], oA[5], oA[6], oA[7]);
    *(uint4*)poB       = make_uint4(oB[0], oB[1], oB[2], oB[3]);
    *(uint4*)(poB + 8) = make_uint4(oB[4], oB[5], oB[6], oB[7]);
}

// ---------------- launch ----------------
extern "C" void kernel_launch(void* const* d_in, const int* in_sizes, int n_in,
                              void* d_out, int out_size, void* d_ws, size_t ws_size,
                              hipStream_t stream)
{
    (void)in_sizes; (void)n_in; (void)out_size; (void)ws_size;
    const float* x      = (const float*)d_in[0];
    const float* radius = (const float*)d_in[1];
    const float* w_in   = (const float*)d_in[2];
    const float* b_in   = (const float*)d_in[3];
    const float* w_out  = (const float*)d_in[4];
    const float* b_out  = (const float*)d_in[5];
    float* outp = (float*)d_out;

    char* ws = (char*)d_ws;
    u16* x_bf    = (u16*)ws;  ws += (size_t)M_ROWS * D_MOD * 2;
    u16* win_bf  = (u16*)ws;  ws += (size_t)QKV_N * D_MOD * 2;
    u16* wout_bf = (u16*)ws;  ws += (size_t)D_MOD * D_MOD * 2;
    u16* qkv_bf  = (u16*)ws;  ws += (size_t)M_ROWS * QKV_N * 2;
    u16* attn_bf = (u16*)ws;

    const int na = M_ROWS * D_MOD;        // 4194304
    const int nb = QKV_N * D_MOD;         // 786432
    const int nc = D_MOD * D_MOD;         // 262144
    cast3_kernel<<<(na + nb + nc) / 2048, 256, 0, stream>>>(
        x, na, w_in, nb, w_out, x_bf, win_bf, wout_bf);

    gemm_bt<true, 128, 192><<<dim3(QKV_N / 192, M_ROWS / 128), 256, 0, stream>>>(
        x_bf, win_bf, b_in, qkv_bf, M_ROWS, QKV_N, D_MOD);
    attn_kernel<<<B_SZ * N_HEAD * (T_LEN / AQ), 256, 0, stream>>>(qkv_bf, radius, attn_bf);
    gemm_bt<false, 64, 128><<<dim3(D_MOD / 128, M_ROWS / 64), 256, 0, stream>>>(
        attn_bf, wout_bf, b_out, outp, M_ROWS, D_MOD, D_MOD);
}